// Round 1
// baseline (9591.726 us; speedup 1.0000x reference)
//
#include <hip/hip_runtime.h>
#include <hip/hip_cooperative_groups.h>

namespace cg = cooperative_groups;

#define N_NODES 100000
#define N_EDGES 3200000
#define N_IN    128
#define N_OUT   64
#define ITERS   150
#define LEAK    0.01f

#define SCAN_CHUNK 1024
#define SCAN_NBLK  98   // 98*1024 = 100352 >= N_NODES+1

__device__ __forceinline__ float mml(float v) {
    v = (v < 0.0f) ? v * LEAK : v;
    if (v > 0.5f) v = 1.0f - 0.25f / v;
    return v;
}

// b_in = biases (then k_scatter_in overwrites the 128 input nodes)
__global__ void k_binit(const float* __restrict__ biases, float* __restrict__ b_in) {
    int i = blockIdx.x * blockDim.x + threadIdx.x;
    if (i < N_NODES) b_in[i] = biases[i];
}

// node_in.at[in_indices].set(in_w * x)  -> last-write-wins for duplicates
__global__ void k_scatter_in(const float* __restrict__ x,
                             const float* __restrict__ in_w,
                             const int*   __restrict__ in_idx,
                             const float* __restrict__ biases,
                             float* __restrict__ b_in) {
    int k = threadIdx.x;
    if (k < N_IN) {
        int idx = in_idx[k];
        bool last = true;
        for (int j = k + 1; j < N_IN; ++j)
            if (in_idx[j] == idx) { last = false; break; }
        if (last) b_in[idx] = biases[idx] + in_w[k] * x[k];
    }
}

// y0 = act(0 + b_in)  (first reference iteration: A @ 0 == 0)
__global__ void k_y0(const float* __restrict__ b_in, float* __restrict__ y0) {
    int i = blockIdx.x * blockDim.x + threadIdx.x;
    if (i < N_NODES) y0[i] = mml(b_in[i]);
}

__global__ void k_hist(const int* __restrict__ rows, int* __restrict__ counts) {
    int i = blockIdx.x * blockDim.x + threadIdx.x;
    int stride = gridDim.x * blockDim.x;
    for (; i < N_EDGES; i += stride) atomicAdd(&counts[rows[i]], 1);
}

// block-local exclusive scan of counts -> rp, block totals -> blockSums
__global__ void k_scan1(const int* __restrict__ counts, int* __restrict__ rp,
                        int* __restrict__ blockSums) {
    __shared__ int sm[SCAN_CHUNK];
    int t = threadIdx.x;
    int i = blockIdx.x * SCAN_CHUNK + t;
    int v = (i < N_NODES) ? counts[i] : 0;
    sm[t] = v;
    __syncthreads();
    for (int off = 1; off < SCAN_CHUNK; off <<= 1) {
        int add = (t >= off) ? sm[t - off] : 0;
        __syncthreads();
        sm[t] += add;
        __syncthreads();
    }
    if (i <= N_NODES) rp[i] = sm[t] - v;   // exclusive within block
    if (t == SCAN_CHUNK - 1) blockSums[blockIdx.x] = sm[t];
}

__global__ void k_scan2(int* __restrict__ blockSums) {
    __shared__ int sm[128];
    int t = threadIdx.x;
    int v = (t < SCAN_NBLK) ? blockSums[t] : 0;
    sm[t] = v;
    __syncthreads();
    for (int off = 1; off < 128; off <<= 1) {
        int add = (t >= off) ? sm[t - off] : 0;
        __syncthreads();
        sm[t] += add;
        __syncthreads();
    }
    if (t < SCAN_NBLK) blockSums[t] = sm[t] - v;  // exclusive block offsets
}

__global__ void k_scan3(int* __restrict__ rp, const int* __restrict__ blockSums,
                        int* __restrict__ next) {
    int i = blockIdx.x * SCAN_CHUNK + threadIdx.x;
    if (i <= N_NODES) {
        int val = rp[i] + blockSums[blockIdx.x];
        rp[i] = val;
        if (i < N_NODES) next[i] = val;
    }
}

// CSR fill: (col, weight) interleaved as int2 for single 8B loads in main loop
__global__ void k_scatter_edges(const int* __restrict__ rows, const int* __restrict__ cols,
                                const float* __restrict__ w,
                                int* __restrict__ next, int2* __restrict__ csr) {
    int i = blockIdx.x * blockDim.x + threadIdx.x;
    int stride = gridDim.x * blockDim.x;
    for (; i < N_EDGES; i += stride) {
        int r = rows[i];
        int p = atomicAdd(&next[r], 1);
        csr[p] = make_int2(cols[i], __float_as_int(w[i]));
    }
}

// Persistent cooperative main loop: 1 grid.sync per iteration, ping-pong y,
// exact-fixed-point early exit (uniform decision post-sync; deadlock-free).
__global__ __launch_bounds__(384, 1) void k_iterate(
    const int*  __restrict__ rp,
    const int2* __restrict__ csr,
    const float* __restrict__ b_in,
    float* __restrict__ ybuf0,
    float* __restrict__ ybuf1,
    int* __restrict__ flags,
    const int* __restrict__ out_idx,
    const float* __restrict__ out_w,
    float* __restrict__ out)
{
    cg::grid_group grid = cg::this_grid();
    const int nb = gridDim.x, b = blockIdx.x;
    const int nt = blockDim.x, t = threadIdx.x;
    // contiguous row range per block: per-CU-balanced, L2-slice stays resident
    const int row_beg = (int)((long long)b       * N_NODES / nb);
    const int row_end = (int)((long long)(b + 1) * N_NODES / nb);
    __shared__ int s_stop;

    const float* ycur = ybuf0;
    float* ynext = ybuf1;

    for (int it = 1; it < ITERS; ++it) {
        int changed = 0;
        for (int row = row_beg + t; row < row_end; row += nt) {
            int e = rp[row];
            const int end = rp[row + 1];
            float a0 = 0.f, a1 = 0.f, a2 = 0.f, a3 = 0.f;
            for (; e + 4 <= end; e += 4) {
                int2 c0 = csr[e];
                int2 c1 = csr[e + 1];
                int2 c2 = csr[e + 2];
                int2 c3 = csr[e + 3];
                a0 += __int_as_float(c0.y) * ycur[c0.x];
                a1 += __int_as_float(c1.y) * ycur[c1.x];
                a2 += __int_as_float(c2.y) * ycur[c2.x];
                a3 += __int_as_float(c3.y) * ycur[c3.x];
            }
            for (; e < end; ++e) {
                int2 c = csr[e];
                a0 += __int_as_float(c.y) * ycur[c.x];
            }
            float v = mml(b_in[row] + ((a0 + a1) + (a2 + a3)));
            changed |= (__float_as_int(v) != __float_as_int(ycur[row]));
            ynext[row] = v;
        }
        if (__any(changed) && (t & 63) == 0) atomicOr(&flags[it], 1);
        grid.sync();
        { const float* tmp = ycur; ycur = ynext; ynext = (float*)tmp; }
        if (t == 0)
            s_stop = (__hip_atomic_load(&flags[it], __ATOMIC_RELAXED,
                                        __HIP_MEMORY_SCOPE_AGENT) == 0);
        __syncthreads();
        if (s_stop) break;   // bitwise fixed point: all later iterations identical
    }

    if (b == 0 && t < N_OUT) out[t] = out_w[t] * ycur[out_idx[t]];
}

extern "C" void kernel_launch(void* const* d_in, const int* in_sizes, int n_in,
                              void* d_out, int out_size, void* d_ws, size_t ws_size,
                              hipStream_t stream) {
    const float* x      = (const float*)d_in[0];
    const float* in_w   = (const float*)d_in[1];
    const float* rec_w  = (const float*)d_in[2];
    const float* biases = (const float*)d_in[3];
    const float* out_w  = (const float*)d_in[4];
    const int*   in_idx = (const int*)d_in[5];
    const int*   e_rows = (const int*)d_in[6];
    const int*   e_cols = (const int*)d_in[7];
    const int*   out_idx= (const int*)d_in[8];
    float* out = (float*)d_out;

    char* ws = (char*)d_ws;
    float* b_in    = (float*)ws;                    // N
    float* y0      = b_in + N_NODES;                // N
    float* y1      = y0 + N_NODES;                  // N
    int*   row_ptr = (int*)(y1 + N_NODES);          // N+1 (+pad)
    int*   next    = row_ptr + (N_NODES + 64);      // N
    int*   counts  = next + N_NODES;                // N
    int*   blockSums = counts + N_NODES;            // 128
    int*   flags   = blockSums + 128;               // ITERS
    size_t off = (size_t)((char*)(flags + ITERS) - ws);
    off = (off + 15) & ~(size_t)15;
    int2* csr = (int2*)(ws + off);                  // N_EDGES int2 (25.6 MB)

    hipMemsetAsync(counts, 0, N_NODES * sizeof(int), stream);
    hipMemsetAsync(flags, 0, ITERS * sizeof(int), stream);

    k_binit<<<391, 256, 0, stream>>>(biases, b_in);
    k_scatter_in<<<1, 128, 0, stream>>>(x, in_w, in_idx, biases, b_in);
    k_y0<<<391, 256, 0, stream>>>(b_in, y0);

    k_hist<<<1024, 256, 0, stream>>>(e_rows, counts);
    k_scan1<<<SCAN_NBLK, SCAN_CHUNK, 0, stream>>>(counts, row_ptr, blockSums);
    k_scan2<<<1, 128, 0, stream>>>(blockSums);
    k_scan3<<<SCAN_NBLK, SCAN_CHUNK, 0, stream>>>(row_ptr, blockSums, next);
    k_scatter_edges<<<1024, 256, 0, stream>>>(e_rows, e_cols, rec_w, next, csr);

    int*   rp_a   = row_ptr;
    int2*  csr_a  = csr;
    float* bin_a  = b_in;
    float* y0_a   = y0;
    float* y1_a   = y1;
    int*   fl_a   = flags;
    void* args[] = { &rp_a, &csr_a, &bin_a, &y0_a, &y1_a, &fl_a,
                     (void*)&out_idx, (void*)&out_w, &out };
    hipLaunchCooperativeKernel((void*)k_iterate, dim3(256), dim3(384),
                               args, 0, stream);
}